// Round 1
// baseline (174.468 us; speedup 1.0000x reference)
//
#include <hip/hip_runtime.h>

#define NB 4
#define NC 128
#define NT 64
#define NHW 1024

// ---------------------------------------------------------------------------
// Kernel 1: partial energy.
// grid = NB*NC*2. Block (bc, half) computes
//   part[bc*2+half][t][s] = sum_{hw in half} x[b,c,t,hw] * y[b,c,s,hw]
// LDS tiles 64 x 64 (stride-padded to 68 floats -> conflict-free reads).
// Each thread owns a 4x4 tile of the 64x64 output: t = tt+16i, s = ss+16j.
// ---------------------------------------------------------------------------
#define K1_S 68
__global__ __launch_bounds__(256, 4) void k_energy(
    const float* __restrict__ x, const float* __restrict__ y,
    float* __restrict__ part)
{
    __shared__ float Xs[NT][K1_S];
    __shared__ float Ys[NT][K1_S];
    const int bc   = blockIdx.x >> 1;
    const int half = blockIdx.x & 1;
    const float* xb = x + (size_t)bc * NT * NHW + half * 512;
    const float* yb = y + (size_t)bc * NT * NHW + half * 512;
    const int tid = threadIdx.x;
    const int tt = tid >> 4, ss = tid & 15;

    float acc[4][4] = {};

    for (int ch = 0; ch < 8; ++ch) {
        __syncthreads();                    // protect LDS from previous compute
        #pragma unroll
        for (int it = 0; it < 4; ++it) {
            int f   = tid + it * 256;       // 0..1023
            int row = f >> 4;               // 16 float4 per 64-float row
            int c4  = f & 15;
            *(float4*)(&Xs[row][c4 * 4]) =
                *(const float4*)(xb + (size_t)row * NHW + ch * 64 + c4 * 4);
            *(float4*)(&Ys[row][c4 * 4]) =
                *(const float4*)(yb + (size_t)row * NHW + ch * 64 + c4 * 4);
        }
        __syncthreads();

        #pragma unroll 4
        for (int k = 0; k < 64; k += 2) {
            float2 xv[4], yv[4];
            #pragma unroll
            for (int i = 0; i < 4; ++i)
                xv[i] = *(const float2*)(&Xs[tt + 16 * i][k]);
            #pragma unroll
            for (int j = 0; j < 4; ++j)
                yv[j] = *(const float2*)(&Ys[ss + 16 * j][k]);
            #pragma unroll
            for (int i = 0; i < 4; ++i)
                #pragma unroll
                for (int j = 0; j < 4; ++j) {
                    acc[i][j] = fmaf(xv[i].x, yv[j].x, acc[i][j]);
                    acc[i][j] = fmaf(xv[i].y, yv[j].y, acc[i][j]);
                }
        }
    }

    float* pb = part + (size_t)blockIdx.x * (NT * NT);
    #pragma unroll
    for (int i = 0; i < 4; ++i)
        #pragma unroll
        for (int j = 0; j < 4; ++j)
            pb[(tt + 16 * i) * NT + (ss + 16 * j)] = acc[i][j];
}

// ---------------------------------------------------------------------------
// Kernel 2: reduce partials over (c, half) and row-softmax of (rowmax - e).
// grid = NB*NT blocks of 64 threads; block = (b,t), thread = s.
// softmax(max - e) stabilized: p_s = exp(min_e - e_s), normalize.
// ---------------------------------------------------------------------------
__global__ void k_softmax(const float* __restrict__ part, float* __restrict__ att)
{
    const int b = blockIdx.x >> 6;
    const int t = blockIdx.x & 63;
    const int s = threadIdx.x;

    const float* p = part + (size_t)b * 256 * (NT * NT) + t * NT + s;
    float e = 0.f;
    #pragma unroll 8
    for (int k = 0; k < 256; ++k)
        e += p[(size_t)k * (NT * NT)];

    float mn = e;
    #pragma unroll
    for (int off = 32; off; off >>= 1)
        mn = fminf(mn, __shfl_xor(mn, off));

    float pv = expf(mn - e);            // exp((max-e) - (max-min)) in [0,1]
    float sum = pv;
    #pragma unroll
    for (int off = 32; off; off >>= 1)
        sum += __shfl_xor(sum, off);

    att[(size_t)blockIdx.x * NT + s] = pv / sum;
}

// ---------------------------------------------------------------------------
// Kernel 3: out[b,c,t,hw] = x[b,c,t,hw] + scale * sum_s A[b,t,s]*y[b,c,s,hw]
// grid = NB*NC*2; block (bc, half) owns 512 hw columns (4 chunks of 128).
// A staged transposed (As[s][t]) so 8 consecutive t's are one float4 pair.
// Thread: 4 columns (col) x 8 t's (group g), loops s with LDS-broadcast A.
// ---------------------------------------------------------------------------
#define K3_SY 132
#define K3_SA 68
__global__ __launch_bounds__(256, 3) void k_out(
    const float* __restrict__ x, const float* __restrict__ y,
    const float* __restrict__ att, const float* __restrict__ scale_p,
    float* __restrict__ out)
{
    __shared__ float As[NT][K3_SA];   // As[s][t]
    __shared__ float Ys[NT][K3_SY];
    const int bc   = blockIdx.x >> 1;
    const int half = blockIdx.x & 1;
    const int b    = bc >> 7;         // bc / NC
    const float scale = scale_p[0];
    const float* xb = x + (size_t)bc * NT * NHW + half * 512;
    const float* yb = y + (size_t)bc * NT * NHW + half * 512;
    float*       ob = out + (size_t)bc * NT * NHW + half * 512;
    const int tid = threadIdx.x;

    // stage A transposed: As[s][t] = att[b][t][s]
    #pragma unroll
    for (int it = 0; it < 16; ++it) {
        int f = tid + it * 256;
        int t = f >> 6, s = f & 63;
        As[s][t] = att[((size_t)b * NT + t) * NT + s];
    }

    const int col = (tid & 31) * 4;   // 4 columns of the 128-wide chunk
    const int g   = tid >> 5;         // t-group: t in [8g, 8g+8)

    for (int ch = 0; ch < 4; ++ch) {
        __syncthreads();              // also covers As staging at ch==0
        #pragma unroll
        for (int it = 0; it < 8; ++it) {
            int f   = tid + it * 256; // 0..2047
            int row = f >> 5;         // 32 float4 per 128-float row
            int c4  = f & 31;
            *(float4*)(&Ys[row][c4 * 4]) =
                *(const float4*)(yb + (size_t)row * NHW + ch * 128 + c4 * 4);
        }
        __syncthreads();

        float4 acc[8] = {};
        #pragma unroll 4
        for (int s = 0; s < NT; ++s) {
            float4 yv = *(const float4*)(&Ys[s][col]);
            float4 al = *(const float4*)(&As[s][8 * g]);
            float4 ah = *(const float4*)(&As[s][8 * g + 4]);
            #define FMA4(A, S) \
                A.x = fmaf(S, yv.x, A.x); A.y = fmaf(S, yv.y, A.y); \
                A.z = fmaf(S, yv.z, A.z); A.w = fmaf(S, yv.w, A.w);
            FMA4(acc[0], al.x) FMA4(acc[1], al.y)
            FMA4(acc[2], al.z) FMA4(acc[3], al.w)
            FMA4(acc[4], ah.x) FMA4(acc[5], ah.y)
            FMA4(acc[6], ah.z) FMA4(acc[7], ah.w)
            #undef FMA4
        }

        #pragma unroll
        for (int r = 0; r < 8; ++r) {
            int t = 8 * g + r;
            float4 xv = *(const float4*)(xb + (size_t)t * NHW + ch * 128 + col);
            float4 o;
            o.x = fmaf(scale, acc[r].x, xv.x);
            o.y = fmaf(scale, acc[r].y, xv.y);
            o.z = fmaf(scale, acc[r].z, xv.z);
            o.w = fmaf(scale, acc[r].w, xv.w);
            *(float4*)(ob + (size_t)t * NHW + ch * 128 + col) = o;
        }
    }
}

// ---------------------------------------------------------------------------
extern "C" void kernel_launch(void* const* d_in, const int* in_sizes, int n_in,
                              void* d_out, int out_size, void* d_ws, size_t ws_size,
                              hipStream_t stream)
{
    const float* x       = (const float*)d_in[0];
    const float* y       = (const float*)d_in[1];
    const float* scale_p = (const float*)d_in[2];
    float* out = (float*)d_out;

    // Scratch: energy partials live in d_out (16.8 MB, overwritten by k_out
    // afterwards); attention (64 KB) lives in d_ws.
    float* part = out;
    float* att  = (float*)d_ws;

    k_energy <<<dim3(NB * NC * 2), 256, 0, stream>>>(x, y, part);
    k_softmax<<<dim3(NB * NT),      64, 0, stream>>>(part, att);
    k_out    <<<dim3(NB * NC * 2), 256, 0, stream>>>(x, y, att, scale_p, out);
}